// Round 1
// baseline (240.272 us; speedup 1.0000x reference)
//
#include <hip/hip_runtime.h>
#include <math.h>

// out[b,s,d] = x[b,s,d] + enc(s,d)
// enc(s,d) = even(d) ? sin(s * 10000^(-d/D)) : cos(s * 10000^(-d/D))
// x: fp32 [B=8, S=4096, D=1024]. Memory-bound streaming add.
//
// Strategy: one thread per (s, d-group-of-4). Compute the 4 enc values once
// (batch-invariant), amortized over the 8 batch images.
//
// v2: the B-loop is restructured loads-first. v1 had `if (b >= B) break;`
// between every load/store pair -> compiler refused to speculate loads across
// the conditional branch -> 1 load in flight per wave (VGPR_Count=24),
// latency-bound at 2.47 TB/s. Here the B==8 hot path issues all 8 independent
// global_load_dwordx4 back-to-back (8 KB in flight per wave), computes the
// transcendentals under the load latency, then does add+store with counted
// vmcnt waits. Target: HBM-bound ~5+ TB/s.

#define S_LEN 4096
#define D_LEN 1024

__global__ __launch_bounds__(256) void pe_add_kernel(
    const float* __restrict__ x, float* __restrict__ out, int B) {
    const int s   = blockIdx.x;           // 0..4095
    const int tid = threadIdx.x;          // 0..255
    const int d0  = tid << 2;             // 4 consecutive dims

    const size_t base    = (size_t)s * D_LEN + (size_t)d0;
    const size_t bstride = (size_t)S_LEN * D_LEN;

    const float sf = (float)s;
    // angle = s * 10000^(-d/D) = s * exp(d * (-ln(10000)/D))
    const float c = -9.210340371976184f / (float)D_LEN;  // -ln(10000)/1024

    if (B == 8) {
        // --- hot path: fixed trip count, no branches between memory ops ---
        // 1) issue all 8 independent loads (compiler clusters these; 8 KB
        //    in flight per wave)
        float4 v[8];
        #pragma unroll
        for (int b = 0; b < 8; ++b) {
            v[b] = *(const float4*)(x + base + (size_t)b * bstride);
        }

        // 2) transcendentals execute while loads are in flight
        const float a0 = sf * expf((float)(d0 + 0) * c);
        const float a1 = sf * expf((float)(d0 + 1) * c);
        const float a2 = sf * expf((float)(d0 + 2) * c);
        const float a3 = sf * expf((float)(d0 + 3) * c);
        // d0 is a multiple of 4: dims d0,d0+2 even -> sin; d0+1,d0+3 odd -> cos
        const float enc0 = sinf(a0);
        const float enc1 = cosf(a1);
        const float enc2 = sinf(a2);
        const float enc3 = cosf(a3);

        // 3) add + store as each load lands (counted vmcnt waits)
        #pragma unroll
        for (int b = 0; b < 8; ++b) {
            float4 t = v[b];
            t.x += enc0;
            t.y += enc1;
            t.z += enc2;
            t.w += enc3;
            *(float4*)(out + base + (size_t)b * bstride) = t;
        }
    } else {
        // --- generic fallback (not perf-critical) ---
        const float a0 = sf * expf((float)(d0 + 0) * c);
        const float a1 = sf * expf((float)(d0 + 1) * c);
        const float a2 = sf * expf((float)(d0 + 2) * c);
        const float a3 = sf * expf((float)(d0 + 3) * c);
        const float enc0 = sinf(a0);
        const float enc1 = cosf(a1);
        const float enc2 = sinf(a2);
        const float enc3 = cosf(a3);

        for (int b = 0; b < B; ++b) {
            const float4* px = (const float4*)(x + base + (size_t)b * bstride);
            float4 t = *px;
            t.x += enc0;
            t.y += enc1;
            t.z += enc2;
            t.w += enc3;
            *(float4*)(out + base + (size_t)b * bstride) = t;
        }
    }
}

extern "C" void kernel_launch(void* const* d_in, const int* in_sizes, int n_in,
                              void* d_out, int out_size, void* d_ws, size_t ws_size,
                              hipStream_t stream) {
    const float* x = (const float*)d_in[0];
    float* out = (float*)d_out;
    const int B = in_sizes[0] / (S_LEN * D_LEN);  // = 8

    dim3 grid(S_LEN);        // one block per sequence position
    dim3 block(D_LEN / 4);   // 256 threads, one float4 each
    pe_add_kernel<<<grid, block, 0, stream>>>(x, out, B);
}

// Round 2
// 240.259 us; speedup vs baseline: 1.0001x; 1.0001x over previous
//
#include <hip/hip_runtime.h>
#include <math.h>

// out[b,s,d] = x[b,s,d] + enc(s,d)
// enc(s,d) = even(d) ? sin(s * 10000^(-d/D)) : cos(s * 10000^(-d/D))
// x: fp32 [B=8, S=4096, D=1024]. Memory-bound streaming add.
//
// v3: two-kernel design.
//   Kernel 1 (enc_kernel): materialize the 16 MB enc table [S][D] into d_ws.
//     Same libm expf/sinf/cosf math as v1 -> bitwise-identical output.
//   Kernel 2 (add_kernel): one thread per float4, NO loops. load x, load enc
//     (L2/L3-hot; blocks ordered batch-fastest so 8 consecutive blocks share
//     one enc row), add, nontemporal store.
//
// Why: v1/v2's per-thread 8-deep batch loop serialized on vmcnt (each wave
// exposed ~8 HBM latencies; VGPR 24-32 shows the compiler never kept >2 loads
// in flight) -> 2.2-2.5 TB/s latency-bound. Removing the chain gives pure
// TLP-hidden streaming (512 waves/CU of work), the shape that hits 6.3 TB/s.

#define S_LEN 4096
#define D_LEN 1024

typedef float f32x4 __attribute__((ext_vector_type(4)));

// ---------- kernel 1: enc table ----------
__global__ __launch_bounds__(256) void enc_kernel(float* __restrict__ enc) {
    const int s  = blockIdx.x;        // 0..4095
    const int d0 = threadIdx.x << 2;  // 4 consecutive dims

    const float sf = (float)s;
    const float c = -9.210340371976184f / (float)D_LEN;  // -ln(10000)/1024

    const float a0 = sf * expf((float)(d0 + 0) * c);
    const float a1 = sf * expf((float)(d0 + 1) * c);
    const float a2 = sf * expf((float)(d0 + 2) * c);
    const float a3 = sf * expf((float)(d0 + 3) * c);
    // d0 multiple of 4: d0, d0+2 even -> sin; d0+1, d0+3 odd -> cos
    f32x4 e;
    e.x = sinf(a0);
    e.y = cosf(a1);
    e.z = sinf(a2);
    e.w = cosf(a3);

    *(f32x4*)(enc + (size_t)s * D_LEN + d0) = e;
}

// ---------- kernel 2: streaming add (B==8 path) ----------
__global__ __launch_bounds__(256) void add_kernel(
    const float* __restrict__ x, const float* __restrict__ enc,
    float* __restrict__ out) {
    // blockIdx.x = s*8 + b : batch fastest -> 8 consecutive blocks reuse the
    // same 4 KB enc row (L2-hit), and writes stay spread across channels.
    const int b = blockIdx.x & 7;
    const int s = blockIdx.x >> 3;

    const size_t row = (size_t)s * D_LEN + ((size_t)threadIdx.x << 2);
    const size_t off = (size_t)b * ((size_t)S_LEN * D_LEN) + row;

    f32x4 e = *(const f32x4*)(enc + row);
    f32x4 v = *(const f32x4*)(x + off);
    v += e;
    // nt store: don't let the out-stream evict enc/x from L2/L3.
    __builtin_nontemporal_store(v, (f32x4*)(out + off));
}

// ---------- fallback (ws too small or B != 8): v1 kernel, known 81 us ----------
__global__ __launch_bounds__(256) void pe_add_fallback(
    const float* __restrict__ x, float* __restrict__ out, int B) {
    const int s   = blockIdx.x;
    const int tid = threadIdx.x;
    const int d0  = tid << 2;

    const float sf = (float)s;
    const float c = -9.210340371976184f / (float)D_LEN;

    float enc0, enc1, enc2, enc3;
    {
        float a0 = sf * expf((float)(d0 + 0) * c);
        float a1 = sf * expf((float)(d0 + 1) * c);
        float a2 = sf * expf((float)(d0 + 2) * c);
        float a3 = sf * expf((float)(d0 + 3) * c);
        enc0 = sinf(a0);
        enc1 = cosf(a1);
        enc2 = sinf(a2);
        enc3 = cosf(a3);
    }

    size_t base = (size_t)s * D_LEN + (size_t)d0;
    const size_t bstride = (size_t)S_LEN * D_LEN;

    for (int b = 0; b < B; ++b) {
        const float4* px = (const float4*)(x + base + (size_t)b * bstride);
        float4 v = *px;
        v.x += enc0;
        v.y += enc1;
        v.z += enc2;
        v.w += enc3;
        *(float4*)(out + base + (size_t)b * bstride) = v;
    }
}

extern "C" void kernel_launch(void* const* d_in, const int* in_sizes, int n_in,
                              void* d_out, int out_size, void* d_ws, size_t ws_size,
                              hipStream_t stream) {
    const float* x = (const float*)d_in[0];
    float* out = (float*)d_out;
    const int B = in_sizes[0] / (S_LEN * D_LEN);  // = 8

    const size_t enc_bytes = (size_t)S_LEN * D_LEN * sizeof(float);  // 16 MB

    if (B == 8 && d_ws != nullptr && ws_size >= enc_bytes) {
        float* enc = (float*)d_ws;
        // 1) build enc table (16 MB, ~5 us)
        enc_kernel<<<dim3(S_LEN), dim3(D_LEN / 4), 0, stream>>>(enc);
        // 2) streaming add: one float4 per thread, 32768 blocks
        add_kernel<<<dim3(S_LEN * 8), dim3(D_LEN / 4), 0, stream>>>(x, enc, out);
    } else {
        pe_add_fallback<<<dim3(S_LEN), dim3(D_LEN / 4), 0, stream>>>(x, out, B);
    }
}

// Round 4
// 236.389 us; speedup vs baseline: 1.0164x; 1.0164x over previous
//
#include <hip/hip_runtime.h>
#include <math.h>

// out[b,s,d] = x[b,s,d] + enc(s,d)
// enc(s,d) = even(d) ? sin(s * 10000^(-d/D)) : cos(s * 10000^(-d/D))
// x: fp32 [B=8, S=4096, D=1024]. Memory-bound streaming add.
//
// v4 (resubmit after infra failure in R3 -- kernel never ran):
// single kernel, one thread per (s, d-group-of-4), all 8 batch loads
// issued as straight-line code and PINNED before everything else with
// __builtin_amdgcn_sched_barrier(0). History:
//   v1 (81us, 2.5 TB/s): per-batch load-add-store chain -> 1 load in flight.
//   v2 (92us): load-loop + store-loop; compiler sank loads to uses (VGPR 32,
//              ~2 in flight) -> chain reconstructed.
//   v3 (enc table + 1-f4-per-thread, ~85us): no chain, but only 1 KB of reads
//              in flight per wave -> Little's-law equilibrium at ~3 TB/s.
// Fix: 8 KB of reads in flight per wave (8x global_load_dwordx4 issued before
// any dependent op; sched_barrier(0) forbids the scheduler from sinking them).
// Transcendentals (4x exp, 2x sin, 2x cos) execute under the load latency.
// Target: read-side saturation, ~45us kernel.

#define S_LEN 4096
#define D_LEN 1024

typedef float f32x4 __attribute__((ext_vector_type(4)));

__global__ __launch_bounds__(256) void pe_add_kernel(
    const float* __restrict__ x, float* __restrict__ out, int B) {
    const int s  = blockIdx.x;           // 0..4095
    const int d0 = threadIdx.x << 2;     // 4 consecutive dims

    const size_t base    = (size_t)s * D_LEN + (size_t)d0;
    const size_t bstride = (size_t)S_LEN * D_LEN;

    const float sf = (float)s;
    // angle = s * 10000^(-d/D) = s * exp(d * (-ln(10000)/D))
    const float c = -9.210340371976184f / (float)D_LEN;  // -ln(10000)/1024

    if (B == 8) {
        const float* p = x + base;
        // --- 1) issue all 8 independent loads, straight-line ---
        f32x4 v0 = *(const f32x4*)(p + 0 * bstride);
        f32x4 v1 = *(const f32x4*)(p + 1 * bstride);
        f32x4 v2 = *(const f32x4*)(p + 2 * bstride);
        f32x4 v3 = *(const f32x4*)(p + 3 * bstride);
        f32x4 v4 = *(const f32x4*)(p + 4 * bstride);
        f32x4 v5 = *(const f32x4*)(p + 5 * bstride);
        f32x4 v6 = *(const f32x4*)(p + 6 * bstride);
        f32x4 v7 = *(const f32x4*)(p + 7 * bstride);
        // Pin: nothing below may be hoisted above, no load may sink below.
        __builtin_amdgcn_sched_barrier(0);

        // --- 2) transcendentals execute while loads are in flight ---
        const float a0 = sf * expf((float)(d0 + 0) * c);
        const float a1 = sf * expf((float)(d0 + 1) * c);
        const float a2 = sf * expf((float)(d0 + 2) * c);
        const float a3 = sf * expf((float)(d0 + 3) * c);
        // d0 multiple of 4: d0, d0+2 even -> sin; d0+1, d0+3 odd -> cos
        f32x4 e;
        e.x = sinf(a0);
        e.y = cosf(a1);
        e.z = sinf(a2);
        e.w = cosf(a3);

        // --- 3) add + store (compiler emits counted vmcnt waits) ---
        v0 += e; v1 += e; v2 += e; v3 += e;
        v4 += e; v5 += e; v6 += e; v7 += e;

        float* q = out + base;
        *(f32x4*)(q + 0 * bstride) = v0;
        *(f32x4*)(q + 1 * bstride) = v1;
        *(f32x4*)(q + 2 * bstride) = v2;
        *(f32x4*)(q + 3 * bstride) = v3;
        *(f32x4*)(q + 4 * bstride) = v4;
        *(f32x4*)(q + 5 * bstride) = v5;
        *(f32x4*)(q + 6 * bstride) = v6;
        *(f32x4*)(q + 7 * bstride) = v7;
    } else {
        // --- generic fallback (not perf-critical) ---
        const float a0 = sf * expf((float)(d0 + 0) * c);
        const float a1 = sf * expf((float)(d0 + 1) * c);
        const float a2 = sf * expf((float)(d0 + 2) * c);
        const float a3 = sf * expf((float)(d0 + 3) * c);
        const float e0 = sinf(a0);
        const float e1 = cosf(a1);
        const float e2 = sinf(a2);
        const float e3 = cosf(a3);

        for (int b = 0; b < B; ++b) {
            const float4* px = (const float4*)(x + base + (size_t)b * bstride);
            float4 t = *px;
            t.x += e0;
            t.y += e1;
            t.z += e2;
            t.w += e3;
            *(float4*)(out + base + (size_t)b * bstride) = t;
        }
    }
}

extern "C" void kernel_launch(void* const* d_in, const int* in_sizes, int n_in,
                              void* d_out, int out_size, void* d_ws, size_t ws_size,
                              hipStream_t stream) {
    const float* x = (const float*)d_in[0];
    float* out = (float*)d_out;
    const int B = in_sizes[0] / (S_LEN * D_LEN);  // = 8

    dim3 grid(S_LEN);        // one block per sequence position
    dim3 block(D_LEN / 4);   // 256 threads, one float4 each
    pe_add_kernel<<<grid, block, 0, stream>>>(x, out, B);
}

// Round 5
// 235.202 us; speedup vs baseline: 1.0216x; 1.0050x over previous
//
#include <hip/hip_runtime.h>
#include <math.h>

// out[b,s,d] = x[b,s,d] + enc(s,d)
// enc(s,d) = even(d) ? sin(s * 10000^(-d/D)) : cos(s * 10000^(-d/D))
// x: fp32 [B=8, S=4096, D=1024]. Memory-bound streaming add.
//
// v5: persistent grid-stride kernel (Guideline 11 shape, = the 6.3 TB/s copy
// ubench shape). History: v1 serial chain 81us, v3 enc-table+max-TLP ~86us,
// v4 pinned-ILP 92us -- ALL one-shot-thread structures, all ~2.5-2.9 TB/s.
// Common flaw: 16K-128K short-lived waves, per-CU outstanding-read pool
// collapses at every wave-churn boundary. Fix: 2048 blocks x 256 threads =
// exactly 8 blocks/CU, ALL waves resident for the whole kernel; each thread
// loops 16x with counted-vmcnt pipelined loads (unroll 4).
//
// Index algebra: flat f4 index i_k = t + k*524288, k=0..15.
//   524288 f4 = 2048 rows exactly -> d-group fixed per thread (c = t%256),
//   s_k alternates between r0 = t/256 and r0+2048, batch b = k/2.
// So enc needs only 4 expf + 8 sin/cos per thread for all 16 f4.

#define S_LEN 4096
#define D_LEN 1024

typedef float f32x4 __attribute__((ext_vector_type(4)));

#define NF4_ROW   256                  // f4 per row (D/4)
#define TSTRIDE   (2048 * 256)         // threads = f4 stride = 524288
#define NITER     16                   // 8.39M f4 / 524288 threads

__global__ __launch_bounds__(256) void pe_add_kernel(
    const float* __restrict__ x, float* __restrict__ out, int B) {
    const int t = blockIdx.x * 256 + threadIdx.x;   // 0..524287

    const float c = -9.210340371976184f / (float)D_LEN;  // -ln(10000)/1024

    if (B == 8) {
        const int col = t & (NF4_ROW - 1);   // f4 column 0..255
        const int r0  = t >> 8;              // 0..2047
        const int d0  = col << 2;            // dims d0..d0+3

        // inv-freq factors, shared by both s values
        const float f0 = expf((float)(d0 + 0) * c);
        const float f1 = expf((float)(d0 + 1) * c);
        const float f2 = expf((float)(d0 + 2) * c);
        const float f3 = expf((float)(d0 + 3) * c);

        const float sa = (float)r0;            // s for even k
        const float sb = (float)(r0 + 2048);   // s for odd k

        // d0 multiple of 4: dims d0,d0+2 even -> sin; d0+1,d0+3 odd -> cos
        f32x4 ea, eb;
        ea.x = sinf(sa * f0); ea.y = cosf(sa * f1);
        ea.z = sinf(sa * f2); ea.w = cosf(sa * f3);
        eb.x = sinf(sb * f0); eb.y = cosf(sb * f1);
        eb.z = sinf(sb * f2); eb.w = cosf(sb * f3);

        const f32x4* px = (const f32x4*)x + t;
        f32x4*       po = (f32x4*)out + t;

        #pragma unroll 4
        for (int k = 0; k < NITER; ++k) {
            f32x4 v = *px;
            v += (k & 1) ? eb : ea;
            // nt store: don't let the out-stream evict x from L3
            __builtin_nontemporal_store(v, po);
            px += TSTRIDE;
            po += TSTRIDE;
        }
    } else {
        // --- generic fallback (not perf-critical): one f4-row chunk per
        // thread over a grid-stride loop in f4 space ---
        const size_t nf4 = (size_t)B * S_LEN * (D_LEN / 4);
        for (size_t i = t; i < nf4; i += (size_t)TSTRIDE) {
            const int col = (int)(i & (NF4_ROW - 1));
            const int s   = (int)((i / NF4_ROW) % S_LEN);
            const int d0  = col << 2;
            const float sf = (float)s;
            f32x4 e;
            e.x = sinf(sf * expf((float)(d0 + 0) * c));
            e.y = cosf(sf * expf((float)(d0 + 1) * c));
            e.z = sinf(sf * expf((float)(d0 + 2) * c));
            e.w = cosf(sf * expf((float)(d0 + 3) * c));
            f32x4 v = ((const f32x4*)x)[i];
            v += e;
            ((f32x4*)out)[i] = v;
        }
    }
}

extern "C" void kernel_launch(void* const* d_in, const int* in_sizes, int n_in,
                              void* d_out, int out_size, void* d_ws, size_t ws_size,
                              hipStream_t stream) {
    const float* x = (const float*)d_in[0];
    float* out = (float*)d_out;
    const int B = in_sizes[0] / (S_LEN * D_LEN);  // = 8

    dim3 grid(2048);    // 8 blocks/CU, all resident: zero wave churn
    dim3 block(256);
    pe_add_kernel<<<grid, block, 0, stream>>>(x, out, B);
}